// Round 1
// baseline (445.576 us; speedup 1.0000x reference)
//
#include <hip/hip_runtime.h>
#include <stdint.h>

#define NSEQ 512
#define DDIM 128
#define NROWS (NSEQ * NSEQ)   // 262144

typedef __bf16 bf16x8 __attribute__((ext_vector_type(8)));
typedef unsigned short u16;
typedef u16 ushort8 __attribute__((ext_vector_type(8)));
typedef float f32x4 __attribute__((ext_vector_type(4)));
typedef uint32_t u32x4 __attribute__((ext_vector_type(4)));
typedef uint32_t u32x2 __attribute__((ext_vector_type(2)));

__device__ __forceinline__ u16 f2bf(float f) {
  uint32_t x = __builtin_bit_cast(uint32_t, f);
  x += 0x7fffu + ((x >> 16) & 1u);   // round-to-nearest-even
  return (u16)(x >> 16);
}
__device__ __forceinline__ float bf2f(u16 u) {
  uint32_t x = ((uint32_t)u) << 16;
  return __builtin_bit_cast(float, x);
}
__device__ __forceinline__ f32x4 mfma_bf16(ushort8 a, ushort8 b, f32x4 c) {
  return __builtin_amdgcn_mfma_f32_16x16x32_bf16(
      __builtin_bit_cast(bf16x8, a), __builtin_bit_cast(bf16x8, b), c, 0, 0, 0);
}
__device__ __forceinline__ float sigmoidf_(float x) {
  return 1.0f / (1.0f + __expf(-x));
}

#define GLOAD16(gp, lp)                                                        \
  __builtin_amdgcn_global_load_lds(                                            \
      (const __attribute__((address_space(1))) void*)(gp),                     \
      (__attribute__((address_space(3))) void*)(lp), 16, 0, 0)

// ---------------------------------------------------------------------------
// K0: weight prep.
//  Wb[e][d] bf16, e in [0,512): e<256 -> p_in_w[e][d]; else g_in_w[e-256][d]
//  Pb[e][d] bf16 = p_out_w[e][d] * norm_out_w[d]   (LN scale folded)
//  Gb[e][d] bf16 = g_out_w[e][d]
//  S12[2e]   = sum_d p_out_w[e][d]*norm_out_w[d]
//  S12[2e+1] = sum_d p_out_w[e][d]*norm_out_b[d]
// ---------------------------------------------------------------------------
__global__ void k0_prep(const float* __restrict__ p_in_w,
                        const float* __restrict__ g_in_w,
                        const float* __restrict__ p_out_w,
                        const float* __restrict__ g_out_w,
                        const float* __restrict__ now,
                        const float* __restrict__ nob,
                        u16* __restrict__ Wb, u16* __restrict__ Pb,
                        u16* __restrict__ Gb, float* __restrict__ S12) {
  const int t = threadIdx.x;  // 256 threads, 1 block
  for (int idx = t; idx < 512 * 128; idx += 256) {
    const int e = idx >> 7, d = idx & 127;
    const float v = (e < 256) ? p_in_w[e * 128 + d] : g_in_w[(e - 256) * 128 + d];
    Wb[idx] = f2bf(v);
  }
  for (int idx = t; idx < 128 * 128; idx += 256) {
    const int d = idx & 127;
    Pb[idx] = f2bf(p_out_w[idx] * now[d]);
    Gb[idx] = f2bf(g_out_w[idx]);
  }
  if (t < 128) {
    float s1 = 0.f, s2 = 0.f;
    for (int d = 0; d < 128; ++d) {
      s1 += p_out_w[t * 128 + d] * now[d];
      s2 += p_out_w[t * 128 + d] * nob[d];
    }
    S12[2 * t] = s1;
    S12[2 * t + 1] = s2;
  }
}

// ---------------------------------------------------------------------------
// K1: LN(x) -> h = (xln @ p_in^T) * sigmoid(xln @ g_in^T) * mask
//     write a = h[:, :128] -> At[d][r],  b = h[:, 128:256] -> Bt[d][r]  (bf16)
// block = 256 thr (4 waves), 64 rows per block.
// ---------------------------------------------------------------------------
__global__ __launch_bounds__(256) void k1_ln_proj(
    const float* __restrict__ x, const float* __restrict__ mask,
    const float* __restrict__ niw, const float* __restrict__ nib,
    const u16* __restrict__ Wb, u16* __restrict__ At, u16* __restrict__ Bt) {
  __shared__ __align__(16) u16 xln[64 * 128];  // [row][128] bf16, XOR-swizzled 16B blocks
  const int tid = threadIdx.x;
  const int lane = tid & 63;
  const int w = tid >> 6;
  const int r0 = blockIdx.x * 64;
  const int g = lane >> 4, c = lane & 15;

  // --- LN phase: wave w handles local rows [w*16, w*16+16), 4 rows/iter ---
#pragma unroll
  for (int it = 0; it < 4; ++it) {
    const int rl = w * 16 + it * 4 + g;
    const float* xr = x + (size_t)(r0 + rl) * DDIM + c * 8;
    f32x4 v0 = *(const f32x4*)xr;
    f32x4 v1 = *(const f32x4*)(xr + 4);
    float s = v0[0] + v0[1] + v0[2] + v0[3] + v1[0] + v1[1] + v1[2] + v1[3];
    float ss = v0[0] * v0[0] + v0[1] * v0[1] + v0[2] * v0[2] + v0[3] * v0[3] +
               v1[0] * v1[0] + v1[1] * v1[1] + v1[2] * v1[2] + v1[3] * v1[3];
#pragma unroll
    for (int m = 1; m < 16; m <<= 1) {
      s += __shfl_xor(s, m);
      ss += __shfl_xor(ss, m);
    }
    const float mu = s * (1.0f / 128.0f);
    const float rs = rsqrtf(ss * (1.0f / 128.0f) - mu * mu + 1e-5f);
    f32x4 w0 = *(const f32x4*)(niw + c * 8);
    f32x4 w1 = *(const f32x4*)(niw + c * 8 + 4);
    f32x4 b0 = *(const f32x4*)(nib + c * 8);
    f32x4 b1 = *(const f32x4*)(nib + c * 8 + 4);
    ushort8 o;
#pragma unroll
    for (int j = 0; j < 4; ++j) o[j] = f2bf((v0[j] - mu) * rs * w0[j] + b0[j]);
#pragma unroll
    for (int j = 0; j < 4; ++j) o[4 + j] = f2bf((v1[j] - mu) * rs * w1[j] + b1[j]);
    const int byteoff = rl * 256 + ((c ^ (rl & 7)) << 4);
    *(ushort8*)((char*)xln + byteoff) = o;
  }
  __syncthreads();

  // --- MFMA phase: wave w owns p-cols [w*64,w*64+64) and g-cols 256+[w*64,..) ---
  const int lr = lane & 15, lq = lane >> 4;
  f32x4 acc[4][8];
#pragma unroll
  for (int m = 0; m < 4; ++m)
#pragma unroll
    for (int n = 0; n < 8; ++n) acc[m][n] = f32x4{0.f, 0.f, 0.f, 0.f};

#pragma unroll
  for (int ks = 0; ks < 4; ++ks) {
    const int kblk = ks * 4 + lq;
    ushort8 af[4];
#pragma unroll
    for (int m = 0; m < 4; ++m) {
      const int row = m * 16 + lr;
      af[m] = *(const ushort8*)((const char*)xln + row * 256 +
                                ((kblk ^ (row & 7)) << 4));
    }
    ushort8 bfr[8];
#pragma unroll
    for (int n = 0; n < 8; ++n) {
      const int e = (n < 4 ? w * 64 + n * 16 : 256 + w * 64 + (n - 4) * 16) + lr;
      const int dd = ks * 32 + lq * 8;
      bfr[n] = *(const ushort8*)(Wb + e * 128 + dd);
    }
#pragma unroll
    for (int m = 0; m < 4; ++m)
#pragma unroll
      for (int n = 0; n < 8; ++n) acc[m][n] = mfma_bf16(af[m], bfr[n], acc[m][n]);
  }

  // --- epilogue: gate, mask, transpose-write to At/Bt ---
  const bool isB = (w >= 2);
  u16* dstbase = isB ? Bt : At;
#pragma unroll
  for (int m = 0; m < 4; ++m) {
    const int rbase = r0 + m * 16 + lq * 4;
    f32x4 mv = *(const f32x4*)(mask + rbase);
#pragma unroll
    for (int np = 0; np < 4; ++np) {
      const int dcol = ((w & 1) * 64) + np * 16 + lr;  // col within At/Bt
      u16* dst = dstbase + (size_t)dcol * NROWS + rbase;
      float o0 = acc[m][np][0] * sigmoidf_(acc[m][np + 4][0]) * mv[0];
      float o1 = acc[m][np][1] * sigmoidf_(acc[m][np + 4][1]) * mv[1];
      float o2 = acc[m][np][2] * sigmoidf_(acc[m][np + 4][2]) * mv[2];
      float o3 = acc[m][np][3] * sigmoidf_(acc[m][np + 4][3]) * mv[3];
      u32x2 pk;
      pk[0] = (uint32_t)f2bf(o0) | ((uint32_t)f2bf(o1) << 16);
      pk[1] = (uint32_t)f2bf(o2) | ((uint32_t)f2bf(o3) << 16);
      *(u32x2*)dst = pk;
    }
  }
}

// ---------------------------------------------------------------------------
// K2: per-d GEMM  t[i][j][d] = sum_k a[i][k][d] * b[j][k][d]
//     C_d(512x512) = A_d @ B_d^T, A/B bf16 K-major.  128x128 tile, BK=64,
//     double-buffered global_load_lds (pre-swizzled source), Ct bf16 out.
// ---------------------------------------------------------------------------
__global__ __launch_bounds__(256) void k2_tri(const u16* __restrict__ At,
                                              const u16* __restrict__ Bt,
                                              u16* __restrict__ Ct) {
  __shared__ __align__(16) u16 lds[2 * 16384];  // [buf][A:8192 | B:8192] elems
  const int tid = threadIdx.x;
  const int bid = blockIdx.x;
  // XCD-chunked swizzle: hw xcd = bid%8 -> give each XCD 16 consecutive d's
  const int lb = (bid & 7) * 256 + (bid >> 3);
  const int d = lb >> 4;
  const int tile = lb & 15;
  const int i0 = (tile >> 2) * 128, j0 = (tile & 3) * 128;
  const u16* Ad = At + (size_t)d * NROWS;
  const u16* Bd = Bt + (size_t)d * NROWS;
  const int lane = tid & 63, wid = tid >> 6;
  const int wr = wid >> 1, wc = wid & 1;
  const int lr = lane & 15, lq = lane >> 4;

  f32x4 acc[4][4];
#pragma unroll
  for (int m = 0; m < 4; ++m)
#pragma unroll
    for (int n = 0; n < 4; ++n) acc[m][n] = f32x4{0.f, 0.f, 0.f, 0.f};

  auto stage = [&](int kt, int buf) {
    const int k0 = kt * 64;
#pragma unroll
    for (int q = 0; q < 4; ++q) {
      const int idx = q * 256 + tid;  // 0..1023
      const int r = idx >> 3, bk = idx & 7;
      const int sbk = bk ^ (r & 7);  // pre-swizzled global source
      GLOAD16(Ad + (size_t)(i0 + r) * NSEQ + k0 + sbk * 8,
              &lds[buf * 16384 + idx * 8]);
      GLOAD16(Bd + (size_t)(j0 + r) * NSEQ + k0 + sbk * 8,
              &lds[buf * 16384 + 8192 + idx * 8]);
    }
  };

  stage(0, 0);
  __syncthreads();
  for (int kt = 0; kt < 8; ++kt) {
    const int buf = kt & 1;
    if (kt < 7) stage(kt + 1, buf ^ 1);
    const u16* A_l = &lds[buf * 16384];
    const u16* B_l = &lds[buf * 16384 + 8192];
#pragma unroll
    for (int ks = 0; ks < 2; ++ks) {
      const int kblk = ks * 4 + lq;
      ushort8 af[4], bfr[4];
#pragma unroll
      for (int m = 0; m < 4; ++m) {
        const int row = wr * 64 + m * 16 + lr;
        af[m] = *(const ushort8*)((const char*)A_l + row * 128 +
                                  ((kblk ^ (row & 7)) << 4));
      }
#pragma unroll
      for (int n = 0; n < 4; ++n) {
        const int col = wc * 64 + n * 16 + lr;
        bfr[n] = *(const ushort8*)((const char*)B_l + col * 128 +
                                   ((kblk ^ (col & 7)) << 4));
      }
#pragma unroll
      for (int m = 0; m < 4; ++m)
#pragma unroll
        for (int n = 0; n < 4; ++n)
          acc[m][n] = mfma_bf16(af[m], bfr[n], acc[m][n]);
    }
    __syncthreads();
  }

  u16* Cd = Ct + (size_t)d * NROWS;
#pragma unroll
  for (int m = 0; m < 4; ++m) {
    const int i = i0 + wr * 64 + m * 16 + lq * 4;
#pragma unroll
    for (int n = 0; n < 4; ++n) {
      const int j = j0 + wc * 64 + n * 16 + lr;
#pragma unroll
      for (int reg = 0; reg < 4; ++reg)
        Cd[(size_t)(i + reg) * NSEQ + j] = f2bf(acc[m][n][reg]);
    }
  }
}

// ---------------------------------------------------------------------------
// K3: out[r][e] = (LN(t[r]) @ Pfold^T + affine) * sigmoid(LN(x[r]) @ G^T)
// block = 256 thr, 128 rows. Waves 0-1 stream Ct (sum/sumsq + LDS transpose),
// waves 2-3 recompute LN(x) into LDS. Then dual MFMA + fused epilogue.
// LN(t) applied as per-row affine: rs*acc + (-rs*mu)*S1[e] + S2[e].
// ---------------------------------------------------------------------------
__global__ __launch_bounds__(256) void k3_out(
    const float* __restrict__ x, const u16* __restrict__ Ct,
    const float* __restrict__ niw, const float* __restrict__ nib,
    const u16* __restrict__ Pb, const u16* __restrict__ Gb,
    const float* __restrict__ S12, float* __restrict__ out) {
  __shared__ __align__(16) u16 ldsX[128 * 128];
  __shared__ __align__(16) u16 ldsT[128 * 128];
  __shared__ __align__(16) float prm[128 * 2];   // {rs, -rs*mu} per row
  __shared__ __align__(16) float s12l[128 * 2];  // {S1,S2} per e
  const int tid = threadIdx.x, lane = tid & 63, w = tid >> 6;
  const int c0 = blockIdx.x * 128;

  if (w < 2) {
    ((u32x2*)s12l)[tid] = ((const u32x2*)S12)[tid];  // 128 thr x 8B = 1KB
    const int cloc = w * 64 + lane;  // == tid
    const u16* cp = Ct + c0 + cloc;
    float s = 0.f, ss = 0.f;
    for (int db = 0; db < 16; ++db) {
      uint32_t pk[4];
#pragma unroll
      for (int j = 0; j < 8; ++j) {
        const u16 u = cp[(size_t)(db * 8 + j) * NROWS];
        const float v = bf2f(u);
        s += v;
        ss += v * v;
        if (j & 1)
          pk[j >> 1] |= ((uint32_t)u) << 16;
        else
          pk[j >> 1] = (uint32_t)u;
      }
      const int byteoff = cloc * 256 + ((db ^ (cloc & 7)) << 4);
      *(u32x4*)((char*)ldsT + byteoff) = u32x4{pk[0], pk[1], pk[2], pk[3]};
    }
    const float mu = s * (1.f / 128.f);
    const float rs = rsqrtf(ss * (1.f / 128.f) - mu * mu + 1e-5f);
    prm[2 * cloc] = rs;
    prm[2 * cloc + 1] = -rs * mu;
  } else {
    const int g = lane >> 4, c = lane & 15;
    for (int it = 0; it < 16; ++it) {
      const int rl = (w - 2) * 64 + it * 4 + g;
      const float* xr = x + (size_t)(c0 + rl) * DDIM + c * 8;
      f32x4 v0 = *(const f32x4*)xr;
      f32x4 v1 = *(const f32x4*)(xr + 4);
      float s = v0[0] + v0[1] + v0[2] + v0[3] + v1[0] + v1[1] + v1[2] + v1[3];
      float ss = v0[0] * v0[0] + v0[1] * v0[1] + v0[2] * v0[2] + v0[3] * v0[3] +
                 v1[0] * v1[0] + v1[1] * v1[1] + v1[2] * v1[2] + v1[3] * v1[3];
#pragma unroll
      for (int m = 1; m < 16; m <<= 1) {
        s += __shfl_xor(s, m);
        ss += __shfl_xor(ss, m);
      }
      const float mu = s * (1.0f / 128.0f);
      const float rs = rsqrtf(ss * (1.0f / 128.0f) - mu * mu + 1e-5f);
      f32x4 w0 = *(const f32x4*)(niw + c * 8);
      f32x4 w1 = *(const f32x4*)(niw + c * 8 + 4);
      f32x4 b0 = *(const f32x4*)(nib + c * 8);
      f32x4 b1 = *(const f32x4*)(nib + c * 8 + 4);
      ushort8 o;
#pragma unroll
      for (int j = 0; j < 4; ++j) o[j] = f2bf((v0[j] - mu) * rs * w0[j] + b0[j]);
#pragma unroll
      for (int j = 0; j < 4; ++j)
        o[4 + j] = f2bf((v1[j] - mu) * rs * w1[j] + b1[j]);
      const int byteoff = rl * 256 + ((c ^ (rl & 7)) << 4);
      *(ushort8*)((char*)ldsX + byteoff) = o;
    }
  }
  __syncthreads();

  // --- dual MFMA: wave w owns rows [w*32, w*32+32) ---
  const int lr = lane & 15, lq = lane >> 4;
  const int rowbase = w * 32;
#pragma unroll
  for (int h = 0; h < 2; ++h) {
    f32x4 aG[2][4], aP[2][4];
#pragma unroll
    for (int m = 0; m < 2; ++m)
#pragma unroll
      for (int n = 0; n < 4; ++n) {
        aG[m][n] = f32x4{0.f, 0.f, 0.f, 0.f};
        aP[m][n] = f32x4{0.f, 0.f, 0.f, 0.f};
      }
#pragma unroll
    for (int ks = 0; ks < 4; ++ks) {
      const int kblk = ks * 4 + lq;
      ushort8 ax[2], at2[2];
#pragma unroll
      for (int m = 0; m < 2; ++m) {
        const int row = rowbase + m * 16 + lr;
        const int off = row * 256 + ((kblk ^ (row & 7)) << 4);
        ax[m] = *(const ushort8*)((const char*)ldsX + off);
        at2[m] = *(const ushort8*)((const char*)ldsT + off);
      }
      ushort8 bg[4], bp[4];
#pragma unroll
      for (int n = 0; n < 4; ++n) {
        const int e = h * 64 + n * 16 + lr;
        const int dd = ks * 32 + lq * 8;
        bg[n] = *(const ushort8*)(Gb + e * 128 + dd);
        bp[n] = *(const ushort8*)(Pb + e * 128 + dd);
      }
#pragma unroll
      for (int m = 0; m < 2; ++m)
#pragma unroll
        for (int n = 0; n < 4; ++n) {
          aG[m][n] = mfma_bf16(ax[m], bg[n], aG[m][n]);
          aP[m][n] = mfma_bf16(at2[m], bp[n], aP[m][n]);
        }
    }
#pragma unroll
    for (int m = 0; m < 2; ++m) {
      const int crow = rowbase + m * 16 + lq * 4;
#pragma unroll
      for (int n = 0; n < 4; ++n) {
        const int e = h * 64 + n * 16 + lr;
        const float s1 = s12l[2 * e], s2v = s12l[2 * e + 1];
#pragma unroll
        for (int reg = 0; reg < 4; ++reg) {
          const float rs = prm[2 * (crow + reg)];
          const float t1 = prm[2 * (crow + reg) + 1];
          const float op = rs * aP[m][n][reg] + t1 * s1 + s2v;
          const float gt = sigmoidf_(aG[m][n][reg]);
          out[(size_t)(c0 + crow + reg) * DDIM + e] = op * gt;
        }
      }
    }
  }
}

// ---------------------------------------------------------------------------
extern "C" void kernel_launch(void* const* d_in, const int* in_sizes, int n_in,
                              void* d_out, int out_size, void* d_ws,
                              size_t ws_size, hipStream_t stream) {
  const float* x = (const float*)d_in[0];
  const float* mask = (const float*)d_in[1];
  const float* niw = (const float*)d_in[2];
  const float* nib = (const float*)d_in[3];
  const float* p_in_w = (const float*)d_in[4];
  const float* g_in_w = (const float*)d_in[5];
  const float* now = (const float*)d_in[6];
  const float* nob = (const float*)d_in[7];
  const float* p_out_w = (const float*)d_in[8];
  const float* g_out_w = (const float*)d_in[9];
  float* out = (float*)d_out;
  char* ws = (char*)d_ws;

  // workspace layout (201.5 MB total)
  u16* At = (u16*)(ws);                    // 128 x 262144 bf16 = 64 MiB
  u16* Bt = (u16*)(ws + 67108864);         // 64 MiB
  u16* Ct = (u16*)(ws + 134217728);        // 64 MiB
  u16* Wb = (u16*)(ws + 201326592);        // 128 KiB
  u16* Pb = (u16*)(ws + 201457664);        // 32 KiB
  u16* Gb = (u16*)(ws + 201490432);        // 32 KiB
  float* S12 = (float*)(ws + 201523200);   // 1 KiB

  hipLaunchKernelGGL(k0_prep, dim3(1), dim3(256), 0, stream, p_in_w, g_in_w,
                     p_out_w, g_out_w, now, nob, Wb, Pb, Gb, S12);
  hipLaunchKernelGGL(k1_ln_proj, dim3(NROWS / 64), dim3(256), 0, stream, x,
                     mask, niw, nib, Wb, At, Bt);
  hipLaunchKernelGGL(k2_tri, dim3(128 * 16), dim3(256), 0, stream, At, Bt, Ct);
  hipLaunchKernelGGL(k3_out, dim3(NROWS / 128), dim3(256), 0, stream, x, Ct,
                     niw, nib, Pb, Gb, S12, out);
}

// Round 2
// 407.495 us; speedup vs baseline: 1.0934x; 1.0934x over previous
//
#include <hip/hip_runtime.h>
#include <stdint.h>

#define NSEQ 512
#define DDIM 128
#define NROWS (NSEQ * NSEQ)   // 262144

typedef __bf16 bf16x8 __attribute__((ext_vector_type(8)));
typedef unsigned short u16;
typedef u16 ushort8 __attribute__((ext_vector_type(8)));
typedef float f32x4 __attribute__((ext_vector_type(4)));
typedef uint32_t u32x4 __attribute__((ext_vector_type(4)));
typedef uint32_t u32x2 __attribute__((ext_vector_type(2)));

__device__ __forceinline__ u16 f2bf(float f) {
  uint32_t x = __builtin_bit_cast(uint32_t, f);
  x += 0x7fffu + ((x >> 16) & 1u);   // round-to-nearest-even
  return (u16)(x >> 16);
}
__device__ __forceinline__ float bf2f(u16 u) {
  uint32_t x = ((uint32_t)u) << 16;
  return __builtin_bit_cast(float, x);
}
__device__ __forceinline__ f32x4 mfma_bf16(ushort8 a, ushort8 b, f32x4 c) {
  return __builtin_amdgcn_mfma_f32_16x16x32_bf16(
      __builtin_bit_cast(bf16x8, a), __builtin_bit_cast(bf16x8, b), c, 0, 0, 0);
}
__device__ __forceinline__ float sigmoidf_(float x) {
  return 1.0f / (1.0f + __expf(-x));
}

#define GLOAD16(gp, lp)                                                        \
  __builtin_amdgcn_global_load_lds(                                            \
      (const __attribute__((address_space(1))) void*)(gp),                     \
      (__attribute__((address_space(3))) void*)(lp), 16, 0, 0)

// ---------------------------------------------------------------------------
// K0: weight prep (unchanged).
// ---------------------------------------------------------------------------
__global__ void k0_prep(const float* __restrict__ p_in_w,
                        const float* __restrict__ g_in_w,
                        const float* __restrict__ p_out_w,
                        const float* __restrict__ g_out_w,
                        const float* __restrict__ now,
                        const float* __restrict__ nob,
                        u16* __restrict__ Wb, u16* __restrict__ Pb,
                        u16* __restrict__ Gb, float* __restrict__ S12) {
  const int t = threadIdx.x;  // 256 threads, 1 block
  for (int idx = t; idx < 512 * 128; idx += 256) {
    const int e = idx >> 7, d = idx & 127;
    const float v = (e < 256) ? p_in_w[e * 128 + d] : g_in_w[(e - 256) * 128 + d];
    Wb[idx] = f2bf(v);
  }
  for (int idx = t; idx < 128 * 128; idx += 256) {
    const int d = idx & 127;
    Pb[idx] = f2bf(p_out_w[idx] * now[d]);
    Gb[idx] = f2bf(g_out_w[idx]);
  }
  if (t < 128) {
    float s1 = 0.f, s2 = 0.f;
    for (int d = 0; d < 128; ++d) {
      s1 += p_out_w[t * 128 + d] * now[d];
      s2 += p_out_w[t * 128 + d] * nob[d];
    }
    S12[2 * t] = s1;
    S12[2 * t + 1] = s2;
  }
}

// ---------------------------------------------------------------------------
// K1 (redesigned): LN(x) -> h = (xln @ p_in^T) * sigmoid(xln @ g_in^T) * mask
// Grid = 8192 blocks: (row-block rb of 64 rows) x (col-group cg of 128 cols).
//   cg=0 -> P-cols e in [0,128)   -> At;  gate cols e+256
//   cg=1 -> P-cols e in [128,256) -> Bt;  gate cols e+256
// Block-id decode keeps (rb, cg=0) and (rb, cg=1) on the SAME XCD (bid%8
// equal, temporally adjacent) so the x rows are fetched once per L2.
// Per wave: 64 rows x (32 P + 32 G cols) -> accP[4][2]+accG[4][2] = 64 VGPR.
// Epilogue: gate+mask -> XOR-swizzled LDS stage [128 d][64 r] -> quads emit
// full 64B-line coalesced dwordx4 stores (no 8B scatter).
// ---------------------------------------------------------------------------
__global__ __launch_bounds__(256, 4) void k1_ln_proj(
    const float* __restrict__ x, const float* __restrict__ mask,
    const float* __restrict__ niw, const float* __restrict__ nib,
    const u16* __restrict__ Wb, u16* __restrict__ At, u16* __restrict__ Bt) {
  __shared__ __align__(16) u16 xln[64 * 128];    // LN rows, 16B-granule XOR swizzle
  __shared__ __align__(16) u16 stage[128 * 64];  // [d][r], 8B-granule XOR swizzle
  const int tid = threadIdx.x;
  const int lane = tid & 63;
  const int w = tid >> 6;
  const int bid = blockIdx.x;
  const int rb = (bid >> 4) * 8 + (bid & 7);
  const int cg = (bid >> 3) & 1;
  const int r0 = rb * 64;
  const int g = lane >> 4, c = lane & 15;

  // --- LN phase: wave w handles local rows [w*16, w*16+16), 4 rows/iter ---
  f32x4 v0[4], v1[4];
#pragma unroll
  for (int it = 0; it < 4; ++it) {
    const int rl = w * 16 + it * 4 + g;
    const float* xr = x + (size_t)(r0 + rl) * DDIM + c * 8;
    v0[it] = *(const f32x4*)xr;
    v1[it] = *(const f32x4*)(xr + 4);
  }
  const f32x4 w0 = *(const f32x4*)(niw + c * 8);
  const f32x4 w1 = *(const f32x4*)(niw + c * 8 + 4);
  const f32x4 b0 = *(const f32x4*)(nib + c * 8);
  const f32x4 b1 = *(const f32x4*)(nib + c * 8 + 4);
#pragma unroll
  for (int it = 0; it < 4; ++it) {
    const int rl = w * 16 + it * 4 + g;
    float s = v0[it][0] + v0[it][1] + v0[it][2] + v0[it][3] +
              v1[it][0] + v1[it][1] + v1[it][2] + v1[it][3];
    float ss = v0[it][0] * v0[it][0] + v0[it][1] * v0[it][1] +
               v0[it][2] * v0[it][2] + v0[it][3] * v0[it][3] +
               v1[it][0] * v1[it][0] + v1[it][1] * v1[it][1] +
               v1[it][2] * v1[it][2] + v1[it][3] * v1[it][3];
#pragma unroll
    for (int m = 1; m < 16; m <<= 1) {
      s += __shfl_xor(s, m);
      ss += __shfl_xor(ss, m);
    }
    const float mu = s * (1.0f / 128.0f);
    const float rs = rsqrtf(ss * (1.0f / 128.0f) - mu * mu + 1e-5f);
    ushort8 o;
#pragma unroll
    for (int j = 0; j < 4; ++j) o[j] = f2bf((v0[it][j] - mu) * rs * w0[j] + b0[j]);
#pragma unroll
    for (int j = 0; j < 4; ++j) o[4 + j] = f2bf((v1[it][j] - mu) * rs * w1[j] + b1[j]);
    const int byteoff = rl * 256 + ((c ^ (rl & 7)) << 4);
    *(ushort8*)((char*)xln + byteoff) = o;
  }
  __syncthreads();

  // --- MFMA phase: wave w owns P-cols eP..eP+32 and G-cols eP+256.. ---
  const int lr = lane & 15, lq = lane >> 4;
  const int eP = cg * 128 + w * 32;
  f32x4 accP[4][2], accG[4][2];
#pragma unroll
  for (int m = 0; m < 4; ++m)
#pragma unroll
    for (int n = 0; n < 2; ++n) {
      accP[m][n] = f32x4{0.f, 0.f, 0.f, 0.f};
      accG[m][n] = f32x4{0.f, 0.f, 0.f, 0.f};
    }

#pragma unroll
  for (int ks = 0; ks < 4; ++ks) {
    const int kblk = ks * 4 + lq;
    ushort8 af[4];
#pragma unroll
    for (int m = 0; m < 4; ++m) {
      const int row = m * 16 + lr;
      af[m] = *(const ushort8*)((const char*)xln + row * 256 +
                                ((kblk ^ (row & 7)) << 4));
    }
    ushort8 bP[2], bG[2];
#pragma unroll
    for (int n = 0; n < 2; ++n) {
      const int e = eP + n * 16 + lr;
      const int dd = ks * 32 + lq * 8;
      bP[n] = *(const ushort8*)(Wb + e * 128 + dd);
      bG[n] = *(const ushort8*)(Wb + (256 + e) * 128 + dd);
    }
#pragma unroll
    for (int m = 0; m < 4; ++m)
#pragma unroll
      for (int n = 0; n < 2; ++n) {
        accP[m][n] = mfma_bf16(af[m], bP[n], accP[m][n]);
        accG[m][n] = mfma_bf16(af[m], bG[n], accG[m][n]);
      }
  }

  // --- epilogue: gate + mask -> swizzled LDS stage [d][r] ---
#pragma unroll
  for (int m = 0; m < 4; ++m) {
    const int rloc = m * 16 + lq * 4;
    const f32x4 mv = *(const f32x4*)(mask + r0 + rloc);
#pragma unroll
    for (int n = 0; n < 2; ++n) {
      const int d = w * 32 + n * 16 + lr;   // col within At/Bt [0,128)
      float o0 = accP[m][n][0] * sigmoidf_(accG[m][n][0]) * mv[0];
      float o1 = accP[m][n][1] * sigmoidf_(accG[m][n][1]) * mv[1];
      float o2 = accP[m][n][2] * sigmoidf_(accG[m][n][2]) * mv[2];
      float o3 = accP[m][n][3] * sigmoidf_(accG[m][n][3]) * mv[3];
      u32x2 pk;
      pk[0] = (uint32_t)f2bf(o0) | ((uint32_t)f2bf(o1) << 16);
      pk[1] = (uint32_t)f2bf(o2) | ((uint32_t)f2bf(o3) << 16);
      const int gsw = (m * 4 + lq) ^ (d & 15);   // 8B granule XOR swizzle
      *(u32x2*)((char*)stage + d * 128 + (gsw << 3)) = pk;
    }
  }
  __syncthreads();

  // --- write phase: quad of 4 lanes emits one full 64B line per round ---
  u16* dstbase = cg ? Bt : At;
  const int q = tid >> 2, il = tid & 3;
#pragma unroll
  for (int r = 0; r < 4; ++r) {
    const int R = q * 4 + r;          // region id [0,256)
    const int d = R >> 1, seg = R & 1;
    const int g0 = seg * 8 + il * 2;  // logical 8B granule
    const u32x2 lo =
        *(const u32x2*)((const char*)stage + d * 128 + ((g0 ^ (d & 15)) << 3));
    const u32x2 hi = *(const u32x2*)((const char*)stage + d * 128 +
                                     (((g0 + 1) ^ (d & 15)) << 3));
    u32x4 outv{lo[0], lo[1], hi[0], hi[1]};
    *(u32x4*)(dstbase + (size_t)d * NROWS + r0 + seg * 32 + il * 8) = outv;
  }
}

// ---------------------------------------------------------------------------
// K2: per-d GEMM  t[i][j][d] = sum_k a[i][k][d] * b[j][k][d]   (unchanged)
// ---------------------------------------------------------------------------
__global__ __launch_bounds__(256) void k2_tri(const u16* __restrict__ At,
                                              const u16* __restrict__ Bt,
                                              u16* __restrict__ Ct) {
  __shared__ __align__(16) u16 lds[2 * 16384];  // [buf][A:8192 | B:8192] elems
  const int tid = threadIdx.x;
  const int bid = blockIdx.x;
  const int lb = (bid & 7) * 256 + (bid >> 3);
  const int d = lb >> 4;
  const int tile = lb & 15;
  const int i0 = (tile >> 2) * 128, j0 = (tile & 3) * 128;
  const u16* Ad = At + (size_t)d * NROWS;
  const u16* Bd = Bt + (size_t)d * NROWS;
  const int lane = tid & 63, wid = tid >> 6;
  const int wr = wid >> 1, wc = wid & 1;
  const int lr = lane & 15, lq = lane >> 4;

  f32x4 acc[4][4];
#pragma unroll
  for (int m = 0; m < 4; ++m)
#pragma unroll
    for (int n = 0; n < 4; ++n) acc[m][n] = f32x4{0.f, 0.f, 0.f, 0.f};

  auto stage = [&](int kt, int buf) {
    const int k0 = kt * 64;
#pragma unroll
    for (int q = 0; q < 4; ++q) {
      const int idx = q * 256 + tid;  // 0..1023
      const int r = idx >> 3, bk = idx & 7;
      const int sbk = bk ^ (r & 7);  // pre-swizzled global source
      GLOAD16(Ad + (size_t)(i0 + r) * NSEQ + k0 + sbk * 8,
              &lds[buf * 16384 + idx * 8]);
      GLOAD16(Bd + (size_t)(j0 + r) * NSEQ + k0 + sbk * 8,
              &lds[buf * 16384 + 8192 + idx * 8]);
    }
  };

  stage(0, 0);
  __syncthreads();
  for (int kt = 0; kt < 8; ++kt) {
    const int buf = kt & 1;
    if (kt < 7) stage(kt + 1, buf ^ 1);
    const u16* A_l = &lds[buf * 16384];
    const u16* B_l = &lds[buf * 16384 + 8192];
#pragma unroll
    for (int ks = 0; ks < 2; ++ks) {
      const int kblk = ks * 4 + lq;
      ushort8 af[4], bfr[4];
#pragma unroll
      for (int m = 0; m < 4; ++m) {
        const int row = wr * 64 + m * 16 + lr;
        af[m] = *(const ushort8*)((const char*)A_l + row * 128 +
                                  ((kblk ^ (row & 7)) << 4));
      }
#pragma unroll
      for (int n = 0; n < 4; ++n) {
        const int col = wc * 64 + n * 16 + lr;
        bfr[n] = *(const ushort8*)((const char*)B_l + col * 128 +
                                   ((kblk ^ (col & 7)) << 4));
      }
#pragma unroll
      for (int m = 0; m < 4; ++m)
#pragma unroll
        for (int n = 0; n < 4; ++n)
          acc[m][n] = mfma_bf16(af[m], bfr[n], acc[m][n]);
    }
    __syncthreads();
  }

  u16* Cd = Ct + (size_t)d * NROWS;
#pragma unroll
  for (int m = 0; m < 4; ++m) {
    const int i = i0 + wr * 64 + m * 16 + lq * 4;
#pragma unroll
    for (int n = 0; n < 4; ++n) {
      const int j = j0 + wc * 64 + n * 16 + lr;
#pragma unroll
      for (int reg = 0; reg < 4; ++reg)
        Cd[(size_t)(i + reg) * NSEQ + j] = f2bf(acc[m][n][reg]);
    }
  }
}

// ---------------------------------------------------------------------------
// K3: out[r][e] = (LN(t[r]) @ Pfold^T + affine) * sigmoid(LN(x[r]) @ G^T)
// (unchanged)
// ---------------------------------------------------------------------------
__global__ __launch_bounds__(256) void k3_out(
    const float* __restrict__ x, const u16* __restrict__ Ct,
    const float* __restrict__ niw, const float* __restrict__ nib,
    const u16* __restrict__ Pb, const u16* __restrict__ Gb,
    const float* __restrict__ S12, float* __restrict__ out) {
  __shared__ __align__(16) u16 ldsX[128 * 128];
  __shared__ __align__(16) u16 ldsT[128 * 128];
  __shared__ __align__(16) float prm[128 * 2];   // {rs, -rs*mu} per row
  __shared__ __align__(16) float s12l[128 * 2];  // {S1,S2} per e
  const int tid = threadIdx.x, lane = tid & 63, w = tid >> 6;
  const int c0 = blockIdx.x * 128;

  if (w < 2) {
    ((u32x2*)s12l)[tid] = ((const u32x2*)S12)[tid];  // 128 thr x 8B = 1KB
    const int cloc = w * 64 + lane;  // == tid
    const u16* cp = Ct + c0 + cloc;
    float s = 0.f, ss = 0.f;
    for (int db = 0; db < 16; ++db) {
      uint32_t pk[4];
#pragma unroll
      for (int j = 0; j < 8; ++j) {
        const u16 u = cp[(size_t)(db * 8 + j) * NROWS];
        const float v = bf2f(u);
        s += v;
        ss += v * v;
        if (j & 1)
          pk[j >> 1] |= ((uint32_t)u) << 16;
        else
          pk[j >> 1] = (uint32_t)u;
      }
      const int byteoff = cloc * 256 + ((db ^ (cloc & 7)) << 4);
      *(u32x4*)((char*)ldsT + byteoff) = u32x4{pk[0], pk[1], pk[2], pk[3]};
    }
    const float mu = s * (1.f / 128.f);
    const float rs = rsqrtf(ss * (1.f / 128.f) - mu * mu + 1e-5f);
    prm[2 * cloc] = rs;
    prm[2 * cloc + 1] = -rs * mu;
  } else {
    const int g = lane >> 4, c = lane & 15;
    for (int it = 0; it < 16; ++it) {
      const int rl = (w - 2) * 64 + it * 4 + g;
      const float* xr = x + (size_t)(c0 + rl) * DDIM + c * 8;
      f32x4 v0 = *(const f32x4*)xr;
      f32x4 v1 = *(const f32x4*)(xr + 4);
      float s = v0[0] + v0[1] + v0[2] + v0[3] + v1[0] + v1[1] + v1[2] + v1[3];
      float ss = v0[0] * v0[0] + v0[1] * v0[1] + v0[2] * v0[2] + v0[3] * v0[3] +
                 v1[0] * v1[0] + v1[1] * v1[1] + v1[2] * v1[2] + v1[3] * v1[3];
#pragma unroll
      for (int m = 1; m < 16; m <<= 1) {
        s += __shfl_xor(s, m);
        ss += __shfl_xor(ss, m);
      }
      const float mu = s * (1.0f / 128.0f);
      const float rs = rsqrtf(ss * (1.0f / 128.0f) - mu * mu + 1e-5f);
      f32x4 w0 = *(const f32x4*)(niw + c * 8);
      f32x4 w1 = *(const f32x4*)(niw + c * 8 + 4);
      f32x4 b0 = *(const f32x4*)(nib + c * 8);
      f32x4 b1 = *(const f32x4*)(nib + c * 8 + 4);
      ushort8 o;
#pragma unroll
      for (int j = 0; j < 4; ++j) o[j] = f2bf((v0[j] - mu) * rs * w0[j] + b0[j]);
#pragma unroll
      for (int j = 0; j < 4; ++j)
        o[4 + j] = f2bf((v1[j] - mu) * rs * w1[j] + b1[j]);
      const int byteoff = rl * 256 + ((c ^ (rl & 7)) << 4);
      *(ushort8*)((char*)ldsX + byteoff) = o;
    }
  }
  __syncthreads();

  // --- dual MFMA: wave w owns rows [w*32, w*32+32) ---
  const int lr = lane & 15, lq = lane >> 4;
  const int rowbase = w * 32;
#pragma unroll
  for (int h = 0; h < 2; ++h) {
    f32x4 aG[2][4], aP[2][4];
#pragma unroll
    for (int m = 0; m < 2; ++m)
#pragma unroll
      for (int n = 0; n < 4; ++n) {
        aG[m][n] = f32x4{0.f, 0.f, 0.f, 0.f};
        aP[m][n] = f32x4{0.f, 0.f, 0.f, 0.f};
      }
#pragma unroll
    for (int ks = 0; ks < 4; ++ks) {
      const int kblk = ks * 4 + lq;
      ushort8 ax[2], at2[2];
#pragma unroll
      for (int m = 0; m < 2; ++m) {
        const int row = rowbase + m * 16 + lr;
        const int off = row * 256 + ((kblk ^ (row & 7)) << 4);
        ax[m] = *(const ushort8*)((const char*)ldsX + off);
        at2[m] = *(const ushort8*)((const char*)ldsT + off);
      }
      ushort8 bg[4], bp[4];
#pragma unroll
      for (int n = 0; n < 4; ++n) {
        const int e = h * 64 + n * 16 + lr;
        const int dd = ks * 32 + lq * 8;
        bg[n] = *(const ushort8*)(Gb + e * 128 + dd);
        bp[n] = *(const ushort8*)(Pb + e * 128 + dd);
      }
#pragma unroll
      for (int m = 0; m < 2; ++m)
#pragma unroll
        for (int n = 0; n < 4; ++n) {
          aG[m][n] = mfma_bf16(ax[m], bg[n], aG[m][n]);
          aP[m][n] = mfma_bf16(at2[m], bp[n], aP[m][n]);
        }
    }
#pragma unroll
    for (int m = 0; m < 2; ++m) {
      const int crow = rowbase + m * 16 + lq * 4;
#pragma unroll
      for (int n = 0; n < 4; ++n) {
        const int e = h * 64 + n * 16 + lr;
        const float s1 = s12l[2 * e], s2v = s12l[2 * e + 1];
#pragma unroll
        for (int reg = 0; reg < 4; ++reg) {
          const float rs = prm[2 * (crow + reg)];
          const float t1 = prm[2 * (crow + reg) + 1];
          const float op = rs * aP[m][n][reg] + t1 * s1 + s2v;
          const float gt = sigmoidf_(aG[m][n][reg]);
          out[(size_t)(c0 + crow + reg) * DDIM + e] = op * gt;
        }
      }
    }
  }
}

// ---------------------------------------------------------------------------
extern "C" void kernel_launch(void* const* d_in, const int* in_sizes, int n_in,
                              void* d_out, int out_size, void* d_ws,
                              size_t ws_size, hipStream_t stream) {
  const float* x = (const float*)d_in[0];
  const float* mask = (const float*)d_in[1];
  const float* niw = (const float*)d_in[2];
  const float* nib = (const float*)d_in[3];
  const float* p_in_w = (const float*)d_in[4];
  const float* g_in_w = (const float*)d_in[5];
  const float* now = (const float*)d_in[6];
  const float* nob = (const float*)d_in[7];
  const float* p_out_w = (const float*)d_in[8];
  const float* g_out_w = (const float*)d_in[9];
  float* out = (float*)d_out;
  char* ws = (char*)d_ws;

  // workspace layout (201.5 MB total)
  u16* At = (u16*)(ws);                    // 128 x 262144 bf16 = 64 MiB
  u16* Bt = (u16*)(ws + 67108864);         // 64 MiB
  u16* Ct = (u16*)(ws + 134217728);        // 64 MiB
  u16* Wb = (u16*)(ws + 201326592);        // 128 KiB
  u16* Pb = (u16*)(ws + 201457664);        // 32 KiB
  u16* Gb = (u16*)(ws + 201490432);        // 32 KiB
  float* S12 = (float*)(ws + 201523200);   // 1 KiB

  hipLaunchKernelGGL(k0_prep, dim3(1), dim3(256), 0, stream, p_in_w, g_in_w,
                     p_out_w, g_out_w, now, nob, Wb, Pb, Gb, S12);
  hipLaunchKernelGGL(k1_ln_proj, dim3(2 * NROWS / 64), dim3(256), 0, stream, x,
                     mask, niw, nib, Wb, At, Bt);
  hipLaunchKernelGGL(k2_tri, dim3(128 * 16), dim3(256), 0, stream, At, Bt, Ct);
  hipLaunchKernelGGL(k3_out, dim3(NROWS / 128), dim3(256), 0, stream, x, Ct,
                     niw, nib, Pb, Gb, S12, out);
}